// Round 1
// baseline (404.921 us; speedup 1.0000x reference)
//
#include <hip/hip_runtime.h>

#define D 1024
#define K 64
#define NROWS 8192

// ---------------------------------------------------------------------------
// k1: M[k,d] = V[k,d] + sum_e W[k,d,e]*x2[e]   (65536 rows, 4KB each)
//     c[k]   = b[k]   + sum_e V[k,D+e]*x2[e]   (64 extra rows)
// One wave per row; x2 staged in LDS; lane reads 4x float4 (16 floats).
// Memory-bound: streams 256 MB of W.
// ---------------------------------------------------------------------------
__global__ __launch_bounds__(256) void k1_wx2(
    const float* __restrict__ W, const float* __restrict__ V,
    const float* __restrict__ x2, const float* __restrict__ b,
    float* __restrict__ M, float* __restrict__ c) {
  __shared__ float xsh[D];
  int t = threadIdx.x;
  ((float4*)xsh)[t] = ((const float4*)x2)[t];  // 256 threads * 16B = 4KB
  __syncthreads();

  int lane = t & 63;
  int wv = t >> 6;
  long row = (long)blockIdx.x * 4 + wv;  // 0..65599
  const long WROWS = (long)K * D;        // 65536

  const float* src;
  bool is_w = (row < WROWS);
  if (is_w) {
    src = W + row * D;
  } else {
    long k = row - WROWS;
    if (k >= K) return;
    src = V + k * (2 * D) + D;  // V[k, D:2D]
  }

  const float4* s4 = (const float4*)src;
  const float4* x4 = (const float4*)xsh;
  float sum = 0.f;
#pragma unroll
  for (int it = 0; it < 4; ++it) {
    float4 w = s4[lane + it * 64];
    float4 xv = x4[lane + it * 64];
    sum += w.x * xv.x + w.y * xv.y + w.z * xv.z + w.w * xv.w;
  }
#pragma unroll
  for (int off = 32; off; off >>= 1) sum += __shfl_down(sum, off, 64);

  if (lane == 0) {
    if (is_w) {
      long k = row >> 10;
      long d = row & (D - 1);
      M[row] = sum + V[k * (2 * D) + d];  // fold V1 into M
    } else {
      long k = row - WROWS;
      c[k] = sum + b[k];
    }
  }
}

// ---------------------------------------------------------------------------
// k2: s[n,k] = sum_d x1[n,d]*M[k,d]; 64x64 output tile per block, BD=32,
// 4x4 register tile/thread (tx=k-group 0..15, ty=n-group 0..15).
// SPLIT=1: two blocks per n-tile each cover 512 d's, write fp32 partials.
// SPLIT=0: full d-range, fused relu(+c)*U epilogue + shuffle reduce over k.
// LDS rows padded to 68 floats: float4-aligned, staging writes 2-way (free).
// ---------------------------------------------------------------------------
template <int SPLIT>
__global__ __launch_bounds__(256) void k2_gemm(
    const float* __restrict__ x1, const float* __restrict__ M,
    const float* __restrict__ c, const float* __restrict__ U,
    float* __restrict__ dst) {
  __shared__ float xs[32][68];
  __shared__ float ms[32][68];
  int t = threadIdx.x;

  int nt, d0, dn;
  if (SPLIT) {
    nt = blockIdx.x >> 1;
    d0 = (blockIdx.x & 1) * (D / 2);
    dn = D / 2;
  } else {
    nt = blockIdx.x;
    d0 = 0;
    dn = D;
  }
  int n_base = nt * 64;
  int tx = t & 15, ty = t >> 4;   // k-group, n-group
  int ld_n = t >> 2, ld_f = t & 3;  // staging: row 0..63, float4-col 0..3 (+4)

  const float4* x1v = (const float4*)(x1 + (long)(n_base + ld_n) * D + d0);
  const float4* Mv = (const float4*)(M + (long)ld_n * D + d0);

  float acc[4][4];
#pragma unroll
  for (int i = 0; i < 4; ++i)
#pragma unroll
    for (int j = 0; j < 4; ++j) acc[i][j] = 0.f;

  for (int dc = 0; dc < dn; dc += 32) {
    int cb = dc >> 2;  // float4 index of chunk start
#pragma unroll
    for (int h = 0; h < 2; ++h) {
      int f4 = ld_f + h * 4;  // 0..7
      float4 xv = x1v[cb + f4];
      float4 mv = Mv[cb + f4];
      int dd = f4 * 4;
      xs[dd + 0][ld_n] = xv.x; xs[dd + 1][ld_n] = xv.y;
      xs[dd + 2][ld_n] = xv.z; xs[dd + 3][ld_n] = xv.w;
      ms[dd + 0][ld_n] = mv.x; ms[dd + 1][ld_n] = mv.y;
      ms[dd + 2][ld_n] = mv.z; ms[dd + 3][ld_n] = mv.w;
    }
    __syncthreads();
#pragma unroll
    for (int d = 0; d < 32; ++d) {
      float4 xv = *(const float4*)&xs[d][ty << 2];
      float4 mv = *(const float4*)&ms[d][tx << 2];
      float xa[4] = {xv.x, xv.y, xv.z, xv.w};
      float ma[4] = {mv.x, mv.y, mv.z, mv.w};
#pragma unroll
      for (int i = 0; i < 4; ++i)
#pragma unroll
        for (int j = 0; j < 4; ++j) acc[i][j] = fmaf(xa[i], ma[j], acc[i][j]);
    }
    __syncthreads();
  }

  if (SPLIT) {
    float* p = dst + (long)(blockIdx.x & 1) * NROWS * K;
#pragma unroll
    for (int i = 0; i < 4; ++i) {
      float4 v = {acc[i][0], acc[i][1], acc[i][2], acc[i][3]};
      *(float4*)&p[(long)(n_base + (ty << 2) + i) * K + (tx << 2)] = v;
    }
  } else {
    float cv[4], uv[4];
#pragma unroll
    for (int j = 0; j < 4; ++j) {
      cv[j] = c[(tx << 2) + j];
      uv[j] = U[(tx << 2) + j];
    }
#pragma unroll
    for (int i = 0; i < 4; ++i) {
      float r = 0.f;
#pragma unroll
      for (int j = 0; j < 4; ++j)
        r += fmaxf(acc[i][j] + cv[j], 0.f) * uv[j];
#pragma unroll
      for (int m = 1; m < 16; m <<= 1) r += __shfl_xor(r, m, 64);
      if (tx == 0) dst[n_base + (ty << 2) + i] = r;
    }
  }
}

// ---------------------------------------------------------------------------
// k3 (split path): out[n] = sum_k relu(pA[n,k]+pB[n,k]+c[k])*U[k]
// One wave per row, lane = k (K==64 exactly).
// ---------------------------------------------------------------------------
__global__ __launch_bounds__(256) void k3_reduce(
    const float* __restrict__ partial, const float* __restrict__ c,
    const float* __restrict__ U, float* __restrict__ out) {
  int t = threadIdx.x;
  int lane = t & 63;
  int n = blockIdx.x * 4 + (t >> 6);
  float a = partial[(long)n * K + lane];
  float bh = partial[(long)NROWS * K + (long)n * K + lane];
  float v = fmaxf(a + bh + c[lane], 0.f) * U[lane];
#pragma unroll
  for (int off = 32; off; off >>= 1) v += __shfl_down(v, off, 64);
  if (lane == 0) out[n] = v;
}

extern "C" void kernel_launch(void* const* d_in, const int* in_sizes, int n_in,
                              void* d_out, int out_size, void* d_ws, size_t ws_size,
                              hipStream_t stream) {
  const float* x1 = (const float*)d_in[0];  // (8192, 1024)
  const float* x2 = (const float*)d_in[1];  // (1, 1024)
  const float* V = (const float*)d_in[2];   // (64, 2048)
  const float* W = (const float*)d_in[3];   // (64, 1024, 1024)
  const float* b = (const float*)d_in[4];   // (64,)
  const float* U = (const float*)d_in[5];   // (64, 1)
  float* out = (float*)d_out;               // (8192, 1)

  float* M = (float*)d_ws;            // 65536 floats (256 KB)
  float* c = M + (long)K * D;         // 64 floats
  float* partial = c + 64;            // 2*8192*64 floats (4 MB), 16B-aligned

  // k1: 65600 rows, 4 waves/block
  k1_wx2<<<dim3(16400), dim3(256), 0, stream>>>(W, V, x2, b, M, c);

  size_t need_split = (size_t)(K * D + 64 + 2 * NROWS * K) * sizeof(float);
  if (ws_size >= need_split) {
    // d-split GEMM: 128 n-tiles * 2 halves = 256 blocks -> all CUs busy
    k2_gemm<1><<<dim3(256), dim3(256), 0, stream>>>(x1, M, c, U, partial);
    k3_reduce<<<dim3(NROWS / 4), dim3(256), 0, stream>>>(partial, c, U, out);
  } else {
    // fallback: single-pass GEMM with fused epilogue (128 blocks)
    k2_gemm<0><<<dim3(128), dim3(256), 0, stream>>>(x1, M, c, U, out);
  }
}

// Round 2
// 404.372 us; speedup vs baseline: 1.0014x; 1.0014x over previous
//
#include <hip/hip_runtime.h>

#define D 1024
#define K 64
#define NROWS 8192

// ---------------------------------------------------------------------------
// k1: M[k,d] = V[k,d] + sum_e W[k,d,e]*x2[e]   (65536 rows, 4KB each)
//     c[k]   = b[k]   + sum_e V[k,D+e]*x2[e]   (64 extra rows)
// One wave per row; x2 staged in LDS; lane reads 4x float4 (16 floats).
// Memory-bound: streams 256 MB of W. Modeled at ~40 us (6.7 TB/s).
// ---------------------------------------------------------------------------
__global__ __launch_bounds__(256) void k1_wx2(
    const float* __restrict__ W, const float* __restrict__ V,
    const float* __restrict__ x2, const float* __restrict__ b,
    float* __restrict__ M, float* __restrict__ c) {
  __shared__ float xsh[D];
  int t = threadIdx.x;
  ((float4*)xsh)[t] = ((const float4*)x2)[t];  // 256 threads * 16B = 4KB
  __syncthreads();

  int lane = t & 63;
  int wv = t >> 6;
  long row = (long)blockIdx.x * 4 + wv;  // 0..65599
  const long WROWS = (long)K * D;        // 65536

  const float* src;
  bool is_w = (row < WROWS);
  if (is_w) {
    src = W + row * D;
  } else {
    long k = row - WROWS;
    if (k >= K) return;
    src = V + k * (2 * D) + D;  // V[k, D:2D]
  }

  const float4* s4 = (const float4*)src;
  const float4* x4 = (const float4*)xsh;
  float sum = 0.f;
#pragma unroll
  for (int it = 0; it < 4; ++it) {
    float4 w = s4[lane + it * 64];
    float4 xv = x4[lane + it * 64];
    sum += w.x * xv.x + w.y * xv.y + w.z * xv.z + w.w * xv.w;
  }
#pragma unroll
  for (int off = 32; off; off >>= 1) sum += __shfl_down(sum, off, 64);

  if (lane == 0) {
    if (is_w) {
      long k = row >> 10;
      long d = row & (D - 1);
      M[row] = sum + V[k * (2 * D) + d];  // fold V1 into M
    } else {
      long k = row - WROWS;
      c[k] = sum + b[k];
    }
  }
}

// ---------------------------------------------------------------------------
// k2: s[n,k] = sum_d x1[n,d]*M[k,d].
// Block tile 256n x 64k, 256 threads, 8n x 8k register tile per thread
// (1 B LDS per FMA -> ~1.5x LDS-bound instead of 3.8x at 4x4).
// NSPLIT-way d-split: each block covers D/NSPLIT d's, writes fp32 partials.
// LDS: xs[16][256] (d-major, no pad: staging writes 2-way = free, reads
// broadcast/2-way), ms[16][64].
// ---------------------------------------------------------------------------
template <int NSPLIT>
__global__ __launch_bounds__(256, 3) void k2_gemm(
    const float* __restrict__ x1, const float* __restrict__ M,
    float* __restrict__ p) {
  __shared__ float xs[16][256];
  __shared__ float ms[16][64];
  int t = threadIdx.x;
  int nt = blockIdx.x / NSPLIT;
  int sp = blockIdx.x % NSPLIT;
  const int DSP = D / NSPLIT;
  int n0 = nt * 256;
  int d0 = sp * DSP;

  int tx = t & 7;   // k-group: k = tx*8 .. +7
  int ty = t >> 3;  // n-group: n = n0 + ty*8 .. +7
  int mk = t & 63;  // M staging: row
  int mg = t >> 6;  // M staging: d-quad 0..3

  const float4* xrow = (const float4*)(x1 + (long)(n0 + t) * D + d0);
  const float4* mrow = (const float4*)(M + (long)mk * D + d0) + mg;

  float acc[8][8];
#pragma unroll
  for (int i = 0; i < 8; ++i)
#pragma unroll
    for (int j = 0; j < 8; ++j) acc[i][j] = 0.f;

#pragma unroll 1
  for (int dc = 0; dc < DSP; dc += 16) {
    // stage x1: thread t owns row n0+t, loads 16 consecutive d's (64B line)
#pragma unroll
    for (int h = 0; h < 4; ++h) {
      float4 v = xrow[(dc >> 2) + h];
      xs[h * 4 + 0][t] = v.x;
      xs[h * 4 + 1][t] = v.y;
      xs[h * 4 + 2][t] = v.z;
      xs[h * 4 + 3][t] = v.w;
    }
    // stage M: thread (mk, mg) loads M[mk, d0+dc+mg*4 .. +3]
    {
      float4 v = mrow[dc >> 2];
      ms[mg * 4 + 0][mk] = v.x;
      ms[mg * 4 + 1][mk] = v.y;
      ms[mg * 4 + 2][mk] = v.z;
      ms[mg * 4 + 3][mk] = v.w;
    }
    __syncthreads();
#pragma unroll
    for (int d = 0; d < 16; ++d) {
      float4 a0 = *(const float4*)&xs[d][ty * 8];
      float4 a1 = *(const float4*)&xs[d][ty * 8 + 4];
      float4 b0 = *(const float4*)&ms[d][tx * 8];
      float4 b1 = *(const float4*)&ms[d][tx * 8 + 4];
      float xa[8] = {a0.x, a0.y, a0.z, a0.w, a1.x, a1.y, a1.z, a1.w};
      float mb[8] = {b0.x, b0.y, b0.z, b0.w, b1.x, b1.y, b1.z, b1.w};
#pragma unroll
      for (int i = 0; i < 8; ++i)
#pragma unroll
        for (int j = 0; j < 8; ++j)
          acc[i][j] = fmaf(xa[i], mb[j], acc[i][j]);
    }
    __syncthreads();
  }

  // write partials: p[sp][n][k]
  float* dst = p + ((long)sp * NROWS + n0 + (long)ty * 8) * K + tx * 8;
#pragma unroll
  for (int i = 0; i < 8; ++i) {
    float4 v0 = {acc[i][0], acc[i][1], acc[i][2], acc[i][3]};
    float4 v1 = {acc[i][4], acc[i][5], acc[i][6], acc[i][7]};
    *(float4*)&dst[(long)i * K] = v0;
    *(float4*)&dst[(long)i * K + 4] = v1;
  }
}

// ---------------------------------------------------------------------------
// k3: out[n] = sum_k relu(sum_sp p[sp,n,k] + c[k]) * U[k]
// One wave per row, lane = k (K==64 exactly). ~16 MB read at NSPLIT=8.
// ---------------------------------------------------------------------------
template <int NSPLIT>
__global__ __launch_bounds__(256) void k3_reduce(
    const float* __restrict__ p, const float* __restrict__ c,
    const float* __restrict__ U, float* __restrict__ out) {
  int t = threadIdx.x;
  int lane = t & 63;
  int n = blockIdx.x * 4 + (t >> 6);
  float s = 0.f;
#pragma unroll
  for (int sp = 0; sp < NSPLIT; ++sp)
    s += p[((long)sp * NROWS + n) * K + lane];
  float v = fmaxf(s + c[lane], 0.f) * U[lane];
#pragma unroll
  for (int off = 32; off; off >>= 1) v += __shfl_down(v, off, 64);
  if (lane == 0) out[n] = v;
}

extern "C" void kernel_launch(void* const* d_in, const int* in_sizes, int n_in,
                              void* d_out, int out_size, void* d_ws, size_t ws_size,
                              hipStream_t stream) {
  const float* x1 = (const float*)d_in[0];  // (8192, 1024)
  const float* x2 = (const float*)d_in[1];  // (1, 1024)
  const float* V = (const float*)d_in[2];   // (64, 2048)
  const float* W = (const float*)d_in[3];   // (64, 1024, 1024)
  const float* b = (const float*)d_in[4];   // (64,)
  const float* U = (const float*)d_in[5];   // (64, 1)
  float* out = (float*)d_out;               // (8192, 1)

  float* M = (float*)d_ws;            // 65536 floats (256 KB)
  float* c = M + (long)K * D;         // 64 floats
  float* partial = c + 64;            // NSPLIT*8192*64 floats, 16B-aligned

  // k1: 65600 rows, 4 waves/block, 1 row/wave
  k1_wx2<<<dim3(16400), dim3(256), 0, stream>>>(W, V, x2, b, M, c);

  size_t need8 = (size_t)(K * D + 64 + 8L * NROWS * K) * sizeof(float);
  if (ws_size >= need8) {
    // 32 n-tiles * 8 d-splits = 256 blocks -> all CUs busy
    k2_gemm<8><<<dim3(256), dim3(256), 0, stream>>>(x1, M, partial);
    k3_reduce<8><<<dim3(NROWS / 4), dim3(256), 0, stream>>>(partial, c, U, out);
  } else {
    // fallback: no split (32 blocks, low occupancy but correct, tiny ws)
    k2_gemm<1><<<dim3(32), dim3(256), 0, stream>>>(x1, M, partial);
    k3_reduce<1><<<dim3(NROWS / 4), dim3(256), 0, stream>>>(partial, c, U, out);
  }
}

// Round 3
// 399.160 us; speedup vs baseline: 1.0144x; 1.0131x over previous
//
#include <hip/hip_runtime.h>

#define D 1024
#define K 64
#define NROWS 8192

// ---------------------------------------------------------------------------
// k1: M[k,d] = V[k,d] + sum_e W[k,d,e]*x2[e]   (65536 rows, 4KB each)
//     c[k]   = b[k]   + sum_e V[k,D+e]*x2[e]   (64 extra rows)
// One wave per row; x2 staged in LDS; lane reads 4x float4 (16 floats).
// Memory-bound: streams 256 MB of W at the ~6.7 TB/s demonstrated ceiling
// (~40 us). This IS the dominant kernel and it is at its traffic floor.
// ---------------------------------------------------------------------------
__global__ __launch_bounds__(256) void k1_wx2(
    const float* __restrict__ W, const float* __restrict__ V,
    const float* __restrict__ x2, const float* __restrict__ b,
    float* __restrict__ M, float* __restrict__ c) {
  __shared__ float xsh[D];
  int t = threadIdx.x;
  ((float4*)xsh)[t] = ((const float4*)x2)[t];  // 256 threads * 16B = 4KB
  __syncthreads();

  int lane = t & 63;
  int wv = t >> 6;
  long row = (long)blockIdx.x * 4 + wv;  // 0..65599
  const long WROWS = (long)K * D;        // 65536

  const float* src;
  bool is_w = (row < WROWS);
  if (is_w) {
    src = W + row * D;
  } else {
    long k = row - WROWS;
    if (k >= K) return;
    src = V + k * (2 * D) + D;  // V[k, D:2D]
  }

  const float4* s4 = (const float4*)src;
  const float4* x4 = (const float4*)xsh;
  float sum = 0.f;
#pragma unroll
  for (int it = 0; it < 4; ++it) {
    float4 w = s4[lane + it * 64];
    float4 xv = x4[lane + it * 64];
    sum += w.x * xv.x + w.y * xv.y + w.z * xv.z + w.w * xv.w;
  }
#pragma unroll
  for (int off = 32; off; off >>= 1) sum += __shfl_down(sum, off, 64);

  if (lane == 0) {
    if (is_w) {
      long k = row >> 10;
      long d = row & (D - 1);
      M[row] = sum + V[k * (2 * D) + d];  // fold V1 into M
    } else {
      long k = row - WROWS;
      c[k] = sum + b[k];
    }
  }
}

// ---------------------------------------------------------------------------
// k2: s[n,k] = sum_d x1[n,d]*M[k,d].
// Block tile 256n x 64k, 256 threads, 8n x 8k register tile (1 B LDS/FMA).
// NSPLIT-way d-split -> 256 blocks. Register-prefetch double buffering:
// chunk i+1's global loads are issued right after the staging barrier so
// they overlap the 1024-FMA compute phase instead of stalling before it.
// ---------------------------------------------------------------------------
template <int NSPLIT>
__global__ __launch_bounds__(256, 3) void k2_gemm(
    const float* __restrict__ x1, const float* __restrict__ M,
    float* __restrict__ p) {
  __shared__ float xs[16][256];
  __shared__ float ms[16][64];
  int t = threadIdx.x;
  int nt = blockIdx.x / NSPLIT;
  int sp = blockIdx.x % NSPLIT;
  const int DSP = D / NSPLIT;
  const int NIT = DSP / 16;
  int n0 = nt * 256;
  int d0 = sp * DSP;

  int tx = t & 7;   // k-group: k = tx*8 .. +7
  int ty = t >> 3;  // n-group: n = n0 + ty*8 .. +7
  int mk = t & 63;  // M staging: row
  int mg = t >> 6;  // M staging: d-quad 0..3

  const float4* xrow = (const float4*)(x1 + (long)(n0 + t) * D + d0);
  const float4* mrow = (const float4*)(M + (long)mk * D + d0) + mg;

  float acc[8][8];
#pragma unroll
  for (int i = 0; i < 8; ++i)
#pragma unroll
    for (int j = 0; j < 8; ++j) acc[i][j] = 0.f;

  // prologue: prefetch chunk 0 into registers
  float4 xreg[4], mreg;
#pragma unroll
  for (int h = 0; h < 4; ++h) xreg[h] = xrow[h];
  mreg = mrow[0];

#pragma unroll 1
  for (int it = 0; it < NIT; ++it) {
    // stage regs -> LDS (x1: thread t owns row n0+t, 16 consecutive d's)
#pragma unroll
    for (int h = 0; h < 4; ++h) {
      xs[h * 4 + 0][t] = xreg[h].x;
      xs[h * 4 + 1][t] = xreg[h].y;
      xs[h * 4 + 2][t] = xreg[h].z;
      xs[h * 4 + 3][t] = xreg[h].w;
    }
    ms[mg * 4 + 0][mk] = mreg.x;
    ms[mg * 4 + 1][mk] = mreg.y;
    ms[mg * 4 + 2][mk] = mreg.z;
    ms[mg * 4 + 3][mk] = mreg.w;
    __syncthreads();

    // prefetch chunk it+1 (overlaps with compute below)
    if (it + 1 < NIT) {
#pragma unroll
      for (int h = 0; h < 4; ++h) xreg[h] = xrow[(it + 1) * 4 + h];
      mreg = mrow[(it + 1) * 4];
    }

#pragma unroll
    for (int d = 0; d < 16; ++d) {
      float4 a0 = *(const float4*)&xs[d][ty * 8];
      float4 a1 = *(const float4*)&xs[d][ty * 8 + 4];
      float4 b0 = *(const float4*)&ms[d][tx * 8];
      float4 b1 = *(const float4*)&ms[d][tx * 8 + 4];
      float xa[8] = {a0.x, a0.y, a0.z, a0.w, a1.x, a1.y, a1.z, a1.w};
      float mb[8] = {b0.x, b0.y, b0.z, b0.w, b1.x, b1.y, b1.z, b1.w};
#pragma unroll
      for (int i = 0; i < 8; ++i)
#pragma unroll
        for (int j = 0; j < 8; ++j)
          acc[i][j] = fmaf(xa[i], mb[j], acc[i][j]);
    }
    __syncthreads();
  }

  // write partials: p[sp][n][k]
  float* dst = p + ((long)sp * NROWS + n0 + (long)ty * 8) * K + tx * 8;
#pragma unroll
  for (int i = 0; i < 8; ++i) {
    float4 v0 = {acc[i][0], acc[i][1], acc[i][2], acc[i][3]};
    float4 v1 = {acc[i][4], acc[i][5], acc[i][6], acc[i][7]};
    *(float4*)&dst[(long)i * K] = v0;
    *(float4*)&dst[(long)i * K + 4] = v1;
  }
}

// ---------------------------------------------------------------------------
// k3: out[n] = sum_k relu(sum_sp p[sp,n,k] + c[k]) * U[k]
// One wave per row, lane = k (K==64 exactly). ~16 MB read at NSPLIT=8.
// ---------------------------------------------------------------------------
template <int NSPLIT>
__global__ __launch_bounds__(256) void k3_reduce(
    const float* __restrict__ p, const float* __restrict__ c,
    const float* __restrict__ U, float* __restrict__ out) {
  int t = threadIdx.x;
  int lane = t & 63;
  int n = blockIdx.x * 4 + (t >> 6);
  float s = 0.f;
#pragma unroll
  for (int sp = 0; sp < NSPLIT; ++sp)
    s += p[((long)sp * NROWS + n) * K + lane];
  float v = fmaxf(s + c[lane], 0.f) * U[lane];
#pragma unroll
  for (int off = 32; off; off >>= 1) v += __shfl_down(v, off, 64);
  if (lane == 0) out[n] = v;
}

extern "C" void kernel_launch(void* const* d_in, const int* in_sizes, int n_in,
                              void* d_out, int out_size, void* d_ws, size_t ws_size,
                              hipStream_t stream) {
  const float* x1 = (const float*)d_in[0];  // (8192, 1024)
  const float* x2 = (const float*)d_in[1];  // (1, 1024)
  const float* V = (const float*)d_in[2];   // (64, 2048)
  const float* W = (const float*)d_in[3];   // (64, 1024, 1024)
  const float* b = (const float*)d_in[4];   // (64,)
  const float* U = (const float*)d_in[5];   // (64, 1)
  float* out = (float*)d_out;               // (8192, 1)

  float* M = (float*)d_ws;            // 65536 floats (256 KB)
  float* c = M + (long)K * D;         // 64 floats
  float* partial = c + 64;            // NSPLIT*8192*64 floats, 16B-aligned

  // k1: 65600 rows, 4 waves/block, 1 row/wave
  k1_wx2<<<dim3(16400), dim3(256), 0, stream>>>(W, V, x2, b, M, c);

  size_t need8 = (size_t)(K * D + 64 + 8L * NROWS * K) * sizeof(float);
  if (ws_size >= need8) {
    // 32 n-tiles * 8 d-splits = 256 blocks -> all CUs busy
    k2_gemm<8><<<dim3(256), dim3(256), 0, stream>>>(x1, M, partial);
    k3_reduce<8><<<dim3(NROWS / 4), dim3(256), 0, stream>>>(partial, c, U, out);
  } else {
    // fallback: no split (32 blocks, low occupancy but correct, tiny ws)
    k2_gemm<1><<<dim3(32), dim3(256), 0, stream>>>(x1, M, partial);
    k3_reduce<1><<<dim3(NROWS / 4), dim3(256), 0, stream>>>(partial, c, U, out);
  }
}